// Round 1
// baseline (232.054 us; speedup 1.0000x reference)
//
#include <hip/hip_runtime.h>
#include <hip/hip_bf16.h>

typedef unsigned short u16;
typedef float f32x4 __attribute__((ext_vector_type(4)));
typedef __bf16 bf16x8 __attribute__((ext_vector_type(8)));

#define B_SZ 8192
#define D_SZ 768
#define TAU_INV 10.0f
// log2(e) / tau
#define LSCALE 14.4269504088896340f

__device__ __forceinline__ void gld_lds16(const u16* g, u16* l) {
    __builtin_amdgcn_global_load_lds((const __attribute__((address_space(1))) void*)g,
                                     (__attribute__((address_space(3))) void*)l,
                                     16, 0, 0);
}

// ---------------- Kernel 1: row norms, bf16 normalize, fp32 diag ----------------
__global__ __launch_bounds__(256) void norm_kernel(const float* __restrict__ v,
                                                   const float* __restrict__ u,
                                                   u16* __restrict__ vn,
                                                   u16* __restrict__ un,
                                                   float* __restrict__ diag) {
    const int row = blockIdx.x;
    const int tid = threadIdx.x;
    const float* vr = v + (size_t)row * D_SZ;
    const float* ur = u + (size_t)row * D_SZ;
    float vv[3], uu[3];
    float sv = 0.f, su = 0.f, sd = 0.f;
#pragma unroll
    for (int c = 0; c < 3; ++c) {
        float a = vr[tid + 256 * c];
        float b = ur[tid + 256 * c];
        vv[c] = a; uu[c] = b;
        sv += a * a; su += b * b; sd += a * b;
    }
#pragma unroll
    for (int m = 1; m < 64; m <<= 1) {
        sv += __shfl_xor(sv, m);
        su += __shfl_xor(su, m);
        sd += __shfl_xor(sd, m);
    }
    __shared__ float red[3][4];
    const int wid = tid >> 6, lane = tid & 63;
    if (lane == 0) { red[0][wid] = sv; red[1][wid] = su; red[2][wid] = sd; }
    __syncthreads();
    sv = red[0][0] + red[0][1] + red[0][2] + red[0][3];
    su = red[1][0] + red[1][1] + red[1][2] + red[1][3];
    sd = red[2][0] + red[2][1] + red[2][2] + red[2][3];
    const float iv = 1.0f / fmaxf(sqrtf(sv), 1e-8f);
    const float iu = 1.0f / fmaxf(sqrtf(su), 1e-8f);
#pragma unroll
    for (int c = 0; c < 3; ++c) {
        __hip_bfloat16 a = __float2bfloat16(vv[c] * iv);
        __hip_bfloat16 b = __float2bfloat16(uu[c] * iu);
        vn[(size_t)row * D_SZ + tid + 256 * c] = *(u16*)&a;
        un[(size_t)row * D_SZ + tid + 256 * c] = *(u16*)&b;
    }
    if (tid == 0) diag[row] = sd * iv * iu * TAU_INV;
}

// ------- Kernel 2: 128x128 bf16 MFMA tile, fused exp + row/col partial sums -------
__global__ __launch_bounds__(256) void simexp_kernel(const u16* __restrict__ vn,
                                                     const u16* __restrict__ un,
                                                     float* __restrict__ rowP,
                                                     float* __restrict__ colP) {
    __shared__ u16 As[128 * 32];
    __shared__ u16 Bs[128 * 32];
    __shared__ float rowLds[2][128];
    __shared__ float colLds[2][128];

    const int tid  = threadIdx.x;
    const int wid  = tid >> 6;
    const int lane = tid & 63;
    const int quad = lane >> 4;
    const int l16  = lane & 15;
    const int wr = wid >> 1, wc = wid & 1;

    // 8x8 chunked grid -> (rb, cb) for L2 locality
    const int id = blockIdx.x;
    const int chunk = id >> 6;
    const int li = id & 63;
    const int rb = ((chunk >> 3) << 3) + (li >> 3);
    const int cb = ((chunk & 7) << 3) + (li & 7);

    // staging: wave `wid` stages 2x16 rows of A and of B, 1 KB per instruction
    const int sr  = lane >> 2;        // row within 16-row segment
    const int sce = (lane & 3) * 8;   // bf16-element offset within row
    const int seg = wid * 32;
    const u16* Ag0 = vn + (size_t)(rb * 128 + seg + sr) * D_SZ + sce;
    const u16* Bg0 = un + (size_t)(cb * 128 + seg + sr) * D_SZ + sce;
    u16* AsB0 = As + seg * 32;
    u16* AsB1 = As + (seg + 16) * 32;
    u16* BsB0 = Bs + seg * 32;
    u16* BsB1 = Bs + (seg + 16) * 32;
    const size_t rstep = (size_t)16 * D_SZ;

    f32x4 acc[4][4];
#pragma unroll
    for (int i = 0; i < 4; ++i)
#pragma unroll
        for (int j = 0; j < 4; ++j) acc[i][j] = (f32x4){0.f, 0.f, 0.f, 0.f};

    for (int k0 = 0; k0 < D_SZ; k0 += 32) {
        __syncthreads();
        gld_lds16(Ag0 + k0, AsB0);
        gld_lds16(Ag0 + rstep + k0, AsB1);
        gld_lds16(Bg0 + k0, BsB0);
        gld_lds16(Bg0 + rstep + k0, BsB1);
        __syncthreads();
        bf16x8 af[4], bfr[4];
#pragma unroll
        for (int i = 0; i < 4; ++i)
            af[i] = *(const bf16x8*)(As + (wr * 64 + i * 16 + l16) * 32 + quad * 8);
#pragma unroll
        for (int j = 0; j < 4; ++j)
            bfr[j] = *(const bf16x8*)(Bs + (wc * 64 + j * 16 + l16) * 32 + quad * 8);
#pragma unroll
        for (int i = 0; i < 4; ++i)
#pragma unroll
            for (int j = 0; j < 4; ++j)
                acc[i][j] = __builtin_amdgcn_mfma_f32_16x16x32_bf16(af[i], bfr[j], acc[i][j], 0, 0, 0);
    }

    // Epilogue: e = exp(sim/tau); per-lane row/col partials.
    // C/D layout: col = lane&15, row (within 16x16 tile) = quad*4 + reg.
    float rowAcc[16];   // [i*4 + r]
    float colAcc[4];    // [j]
#pragma unroll
    for (int t = 0; t < 16; ++t) rowAcc[t] = 0.f;
#pragma unroll
    for (int j = 0; j < 4; ++j) colAcc[j] = 0.f;
#pragma unroll
    for (int i = 0; i < 4; ++i)
#pragma unroll
        for (int j = 0; j < 4; ++j)
#pragma unroll
            for (int r = 0; r < 4; ++r) {
                float e = exp2f(acc[i][j][r] * LSCALE);
                rowAcc[i * 4 + r] += e;
                colAcc[j] += e;
            }
    // rows: reduce across the 16 lanes of each quad (cols of each tile)
#pragma unroll
    for (int m = 1; m < 16; m <<= 1)
#pragma unroll
        for (int t = 0; t < 16; ++t) rowAcc[t] += __shfl_xor(rowAcc[t], m);
    // cols: reduce across quads (rows of each tile)
#pragma unroll
    for (int m = 16; m < 64; m <<= 1)
#pragma unroll
        for (int j = 0; j < 4; ++j) colAcc[j] += __shfl_xor(colAcc[j], m);

    // lane l16 writes element t=l16 (predicated stores avoid dynamic reg indexing)
#pragma unroll
    for (int t = 0; t < 16; ++t)
        if (l16 == t)
            rowLds[wc][wr * 64 + (t >> 2) * 16 + quad * 4 + (t & 3)] = rowAcc[t];
    if (quad == 0) {
#pragma unroll
        for (int j = 0; j < 4; ++j)
            colLds[wr][wc * 64 + j * 16 + l16] = colAcc[j];
    }
    __syncthreads();
    if (tid < 128) {
        rowP[(size_t)cb * B_SZ + rb * 128 + tid] = rowLds[0][tid] + rowLds[1][tid];
    } else {
        const int t = tid - 128;
        colP[(size_t)rb * B_SZ + cb * 128 + t] = colLds[0][t] + colLds[1][t];
    }
}

// ---------------- Kernel 3: reduce partials, log, subtract diag, mean ----------------
__global__ __launch_bounds__(256) void finalize_kernel(const float* __restrict__ rowP,
                                                       const float* __restrict__ colP,
                                                       const float* __restrict__ diag,
                                                       float* __restrict__ out) {
    const int i = blockIdx.x * 256 + threadIdx.x;
    float rs = 0.f, cs = 0.f;
#pragma unroll 8
    for (int p = 0; p < 64; ++p) {
        rs += rowP[(size_t)p * B_SZ + i];
        cs += colP[(size_t)p * B_SZ + i];
    }
    float contrib = (0.75f * logf(rs) + 0.25f * logf(cs) - diag[i]) * (1.0f / (float)B_SZ);
#pragma unroll
    for (int m = 1; m < 64; m <<= 1) contrib += __shfl_xor(contrib, m);
    __shared__ float red[4];
    const int wid = threadIdx.x >> 6, lane = threadIdx.x & 63;
    if (lane == 0) red[wid] = contrib;
    __syncthreads();
    if (threadIdx.x == 0) atomicAdd(out, red[0] + red[1] + red[2] + red[3]);
}

extern "C" void kernel_launch(void* const* d_in, const int* in_sizes, int n_in,
                              void* d_out, int out_size, void* d_ws, size_t ws_size,
                              hipStream_t stream) {
    const float* v = (const float*)d_in[0];
    const float* u = (const float*)d_in[1];
    char* ws = (char*)d_ws;
    // workspace layout (29.4 MB total)
    u16* vn    = (u16*)(ws);                    // 8192*768*2  = 12,582,912
    u16* un    = (u16*)(ws + 12582912);         // 12,582,912
    float* dg  = (float*)(ws + 25165824);       // 8192*4      = 32,768
    float* rwp = (float*)(ws + 25198592);       // 64*8192*4   = 2,097,152
    float* clp = (float*)(ws + 27295744);       // 2,097,152
    float* out = (float*)d_out;

    hipMemsetAsync(out, 0, sizeof(float), stream);
    hipLaunchKernelGGL(norm_kernel, dim3(8192), dim3(256), 0, stream, v, u, vn, un, dg);
    hipLaunchKernelGGL(simexp_kernel, dim3(4096), dim3(256), 0, stream, vn, un, rwp, clp);
    hipLaunchKernelGGL(finalize_kernel, dim3(B_SZ / 256), dim3(256), 0, stream, rwp, clp, dg, out);
}

// Round 2
// 195.428 us; speedup vs baseline: 1.1874x; 1.1874x over previous
//
#include <hip/hip_runtime.h>
#include <hip/hip_bf16.h>
#include <hip/hip_fp8.h>

typedef unsigned char u8;
typedef unsigned int u32;
typedef float f32x4 __attribute__((ext_vector_type(4)));
typedef float f32x16 __attribute__((ext_vector_type(16)));
typedef int i32x8 __attribute__((ext_vector_type(8)));

#define B_SZ 8192
#define D_SZ 768
#define TAU_INV 10.0f
// values scaled by 16 -> logits scaled by 256; exp2 constant = log2(e)*10/256
#define ESCALE 0.05635527503472513f
#define FP8_SCALE 16.0f

__device__ __forceinline__ void gld_lds16(const u8* g, u8* l) {
    __builtin_amdgcn_global_load_lds((const __attribute__((address_space(1))) void*)g,
                                     (__attribute__((address_space(3))) void*)l,
                                     16, 0, 0);
}

__device__ __forceinline__ u8 to_fp8(float x) {
    return (u8)__hip_cvt_float_to_fp8(x, __HIP_SATFINITE, __HIP_E4M3);
}

// ---------------- Kernel 1: row norms, fp8 normalize (x16), fp32 diag ----------------
// 192 threads = 3 waves, one row per block, float4 loads, packed u32 fp8 stores.
__global__ __launch_bounds__(192) void norm_kernel(const float4* __restrict__ v,
                                                   const float4* __restrict__ u,
                                                   u32* __restrict__ vn,
                                                   u32* __restrict__ un,
                                                   float* __restrict__ diag) {
    const int row = blockIdx.x;
    const int tid = threadIdx.x;
    const int idx = row * 192 + tid;
    float4 a = v[idx];
    float4 b = u[idx];
    float sv = a.x * a.x + a.y * a.y + a.z * a.z + a.w * a.w;
    float su = b.x * b.x + b.y * b.y + b.z * b.z + b.w * b.w;
    float sd = a.x * b.x + a.y * b.y + a.z * b.z + a.w * b.w;
#pragma unroll
    for (int m = 1; m < 64; m <<= 1) {
        sv += __shfl_xor(sv, m);
        su += __shfl_xor(su, m);
        sd += __shfl_xor(sd, m);
    }
    __shared__ float red[3][3];
    const int wid = tid >> 6, lane = tid & 63;
    if (lane == 0) { red[0][wid] = sv; red[1][wid] = su; red[2][wid] = sd; }
    __syncthreads();
    sv = red[0][0] + red[0][1] + red[0][2];
    su = red[1][0] + red[1][1] + red[1][2];
    sd = red[2][0] + red[2][1] + red[2][2];
    const float iv = FP8_SCALE / fmaxf(sqrtf(sv), 1e-8f);
    const float iu = FP8_SCALE / fmaxf(sqrtf(su), 1e-8f);
    u32 pa = (u32)to_fp8(a.x * iv) | ((u32)to_fp8(a.y * iv) << 8) |
             ((u32)to_fp8(a.z * iv) << 16) | ((u32)to_fp8(a.w * iv) << 24);
    u32 pb = (u32)to_fp8(b.x * iu) | ((u32)to_fp8(b.y * iu) << 8) |
             ((u32)to_fp8(b.z * iu) << 16) | ((u32)to_fp8(b.w * iu) << 24);
    vn[idx] = pa;
    un[idx] = pb;
    if (tid == 0) diag[row] = sd * iv * iu * TAU_INV / (FP8_SCALE * FP8_SCALE);
}

// ------- Kernel 2: 128x128 fp8 MX MFMA tile (BK=64), fused exp + row/col partials -------
__global__ __launch_bounds__(256) void simexp_kernel(const u8* __restrict__ vn,
                                                     const u8* __restrict__ un,
                                                     float* __restrict__ rowP,
                                                     float* __restrict__ colP) {
    __shared__ __align__(64) u8 As[128 * 64];
    __shared__ __align__(64) u8 Bs[128 * 64];
    __shared__ float rowLds[2][128];
    __shared__ float colLds[2][128];

    const int tid  = threadIdx.x;
    const int wid  = tid >> 6;
    const int lane = tid & 63;
    const int l32  = lane & 31;
    const int h    = lane >> 5;
    const int wr = wid >> 1, wc = wid & 1;

    // 8x8 chunked grid for L2 locality
    const int id = blockIdx.x;
    const int chunk = id >> 6;
    const int li = id & 63;
    const int rb = ((chunk >> 3) << 3) + (li >> 3);
    const int cb = ((chunk & 7) << 3) + (li & 7);

    // staging: wave stages 32 rows of A and 32 rows of B per K-iter (2 calls each)
    const int sr = lane >> 2;           // row within 16-row segment
    const int sc = (lane & 3) * 16;     // byte offset within 64B chunk
    const u8* Ag0 = vn + (size_t)(rb * 128 + wid * 32 + sr) * D_SZ + sc;
    const u8* Bg0 = un + (size_t)(cb * 128 + wid * 32 + sr) * D_SZ + sc;
    const size_t rstep = (size_t)16 * D_SZ;
    u8* AsD0 = As + (wid * 32) * 64;
    u8* AsD1 = As + (wid * 32 + 16) * 64;
    u8* BsD0 = Bs + (wid * 32) * 64;
    u8* BsD1 = Bs + (wid * 32 + 16) * 64;

    f32x16 acc[2][2];
#pragma unroll
    for (int i = 0; i < 2; ++i)
#pragma unroll
        for (int j = 0; j < 2; ++j)
#pragma unroll
            for (int r = 0; r < 16; ++r) acc[i][j][r] = 0.f;

    for (int k0 = 0; k0 < D_SZ; k0 += 64) {
        __syncthreads();
        gld_lds16(Ag0 + k0, AsD0);
        gld_lds16(Ag0 + rstep + k0, AsD1);
        gld_lds16(Bg0 + k0, BsD0);
        gld_lds16(Bg0 + rstep + k0, BsD1);
        __syncthreads();
        i32x8 af[2], bf[2];
#pragma unroll
        for (int i = 0; i < 2; ++i)
            af[i] = *(const i32x8*)(As + (wr * 64 + i * 32 + l32) * 64 + h * 32);
#pragma unroll
        for (int j = 0; j < 2; ++j)
            bf[j] = *(const i32x8*)(Bs + (wc * 64 + j * 32 + l32) * 64 + h * 32);
#pragma unroll
        for (int i = 0; i < 2; ++i)
#pragma unroll
            for (int j = 0; j < 2; ++j)
                acc[i][j] = __builtin_amdgcn_mfma_scale_f32_32x32x64_f8f6f4(
                    af[i], bf[j], acc[i][j], 0, 0, 0, 0x7F7F7F7F, 0, 0x7F7F7F7F);
    }

    // Epilogue. 32x32 C/D layout: col = lane&31, row = (reg&3) + 8*(reg>>2) + 4*h
    float rowAcc[32];   // [i*16 + reg]
    float colAcc[2];    // [j]
#pragma unroll
    for (int t = 0; t < 32; ++t) rowAcc[t] = 0.f;
    colAcc[0] = 0.f; colAcc[1] = 0.f;
#pragma unroll
    for (int i = 0; i < 2; ++i)
#pragma unroll
        for (int j = 0; j < 2; ++j)
#pragma unroll
            for (int r = 0; r < 16; ++r) {
                float e = exp2f(acc[i][j][r] * ESCALE);
                rowAcc[i * 16 + r] += e;
                colAcc[j] += e;
            }
    // row sums: reduce across the 32 cols (lanes with same h)
#pragma unroll
    for (int m = 1; m < 32; m <<= 1)
#pragma unroll
        for (int t = 0; t < 32; ++t) rowAcc[t] += __shfl_xor(rowAcc[t], m);
    // col sums: add the other h half (rows)
    colAcc[0] += __shfl_xor(colAcc[0], 32);
    colAcc[1] += __shfl_xor(colAcc[1], 32);

    // writers: row (i,reg) written by lanes with l32==reg (one per h)
#pragma unroll
    for (int i = 0; i < 2; ++i)
#pragma unroll
        for (int t = 0; t < 16; ++t)
            if (l32 == t) {
                int row = wr * 64 + i * 32 + (t & 3) + 8 * (t >> 2) + 4 * h;
                rowLds[wc][row] = rowAcc[i * 16 + t];
            }
    if (h == 0) {
#pragma unroll
        for (int j = 0; j < 2; ++j)
            colLds[wr][wc * 64 + j * 32 + l32] = colAcc[j];
    }
    __syncthreads();
    if (tid < 128) {
        rowP[(size_t)cb * B_SZ + rb * 128 + tid] = rowLds[0][tid] + rowLds[1][tid];
    } else {
        const int t = tid - 128;
        colP[(size_t)rb * B_SZ + cb * 128 + t] = colLds[0][t] + colLds[1][t];
    }
}

// ---------------- Kernel 3: reduce partials, log, subtract diag, mean ----------------
__global__ __launch_bounds__(256) void finalize_kernel(const float* __restrict__ rowP,
                                                       const float* __restrict__ colP,
                                                       const float* __restrict__ diag,
                                                       float* __restrict__ out) {
    const int i = blockIdx.x * 256 + threadIdx.x;
    float rs = 0.f, cs = 0.f;
#pragma unroll 8
    for (int p = 0; p < 64; ++p) {
        rs += rowP[(size_t)p * B_SZ + i];
        cs += colP[(size_t)p * B_SZ + i];
    }
    float contrib = (0.75f * logf(rs) + 0.25f * logf(cs) - diag[i]) * (1.0f / (float)B_SZ);
#pragma unroll
    for (int m = 1; m < 64; m <<= 1) contrib += __shfl_xor(contrib, m);
    __shared__ float red[4];
    const int wid = threadIdx.x >> 6, lane = threadIdx.x & 63;
    if (lane == 0) red[wid] = contrib;
    __syncthreads();
    if (threadIdx.x == 0) atomicAdd(out, red[0] + red[1] + red[2] + red[3]);
}

extern "C" void kernel_launch(void* const* d_in, const int* in_sizes, int n_in,
                              void* d_out, int out_size, void* d_ws, size_t ws_size,
                              hipStream_t stream) {
    const float* v = (const float*)d_in[0];
    const float* u = (const float*)d_in[1];
    char* ws = (char*)d_ws;
    // workspace layout (~16.7 MB)
    u8* vn8    = (u8*)(ws);                     // 8192*768    = 6,291,456
    u8* un8    = (u8*)(ws + 6291456);           // 6,291,456
    float* dg  = (float*)(ws + 12582912);       // 8192*4      = 32,768
    float* rwp = (float*)(ws + 12615680);       // 64*8192*4   = 2,097,152
    float* clp = (float*)(ws + 14712832);       // 2,097,152
    float* out = (float*)d_out;

    hipMemsetAsync(out, 0, sizeof(float), stream);
    hipLaunchKernelGGL(norm_kernel, dim3(8192), dim3(192), 0, stream,
                       (const float4*)v, (const float4*)u, (u32*)vn8, (u32*)un8, dg);
    hipLaunchKernelGGL(simexp_kernel, dim3(4096), dim3(256), 0, stream, vn8, un8, rwp, clp);
    hipLaunchKernelGGL(finalize_kernel, dim3(B_SZ / 256), dim3(256), 0, stream, rwp, clp, dg, out);
}

// Round 3
// 182.549 us; speedup vs baseline: 1.2712x; 1.0706x over previous
//
#include <hip/hip_runtime.h>
#include <hip/hip_bf16.h>
#include <hip/hip_fp8.h>

typedef unsigned char u8;
typedef unsigned int u32;
typedef float f32x16 __attribute__((ext_vector_type(16)));
typedef int i32x4 __attribute__((ext_vector_type(4)));
typedef int i32x8 __attribute__((ext_vector_type(8)));

#define B_SZ 8192
#define D_SZ 768
#define TAU_INV 10.0f
// values scaled by 16 -> logits scaled by 256; exp2 constant = log2(e)*10/256
#define ESCALE 0.05635527503472513f
#define FP8_SCALE 16.0f

__device__ __forceinline__ void gld_lds16(const u8* g, u8* l) {
    __builtin_amdgcn_global_load_lds((const __attribute__((address_space(1))) void*)g,
                                     (__attribute__((address_space(3))) void*)l,
                                     16, 0, 0);
}

__device__ __forceinline__ u8 to_fp8(float x) {
    return (u8)__hip_cvt_float_to_fp8(x, __HIP_SATFINITE, __HIP_E4M3);
}

// ---------------- Kernel 1: row norms, fp8 normalize (x16), fp32 diag ----------------
// 256 threads = 4 waves, one row per WAVE, wave-shuffle reduce only (no barrier).
__global__ __launch_bounds__(256) void norm_kernel(const float4* __restrict__ v,
                                                   const float4* __restrict__ u,
                                                   u32* __restrict__ vn,
                                                   u32* __restrict__ un,
                                                   float* __restrict__ diag) {
    const int wid = threadIdx.x >> 6, lane = threadIdx.x & 63;
    const int row = blockIdx.x * 4 + wid;
    const float4* vr = v + (size_t)row * 192;
    const float4* ur = u + (size_t)row * 192;
    float4 a[3], b[3];
    float sv = 0.f, su = 0.f, sd = 0.f;
#pragma unroll
    for (int c = 0; c < 3; ++c) {
        a[c] = vr[lane + 64 * c];
        b[c] = ur[lane + 64 * c];
        sv += a[c].x * a[c].x + a[c].y * a[c].y + a[c].z * a[c].z + a[c].w * a[c].w;
        su += b[c].x * b[c].x + b[c].y * b[c].y + b[c].z * b[c].z + b[c].w * b[c].w;
        sd += a[c].x * b[c].x + a[c].y * b[c].y + a[c].z * b[c].z + a[c].w * b[c].w;
    }
#pragma unroll
    for (int m = 1; m < 64; m <<= 1) {
        sv += __shfl_xor(sv, m);
        su += __shfl_xor(su, m);
        sd += __shfl_xor(sd, m);
    }
    const float iv = FP8_SCALE / fmaxf(sqrtf(sv), 1e-8f);
    const float iu = FP8_SCALE / fmaxf(sqrtf(su), 1e-8f);
#pragma unroll
    for (int c = 0; c < 3; ++c) {
        u32 pa = (u32)to_fp8(a[c].x * iv) | ((u32)to_fp8(a[c].y * iv) << 8) |
                 ((u32)to_fp8(a[c].z * iv) << 16) | ((u32)to_fp8(a[c].w * iv) << 24);
        u32 pb = (u32)to_fp8(b[c].x * iu) | ((u32)to_fp8(b[c].y * iu) << 8) |
                 ((u32)to_fp8(b[c].z * iu) << 16) | ((u32)to_fp8(b[c].w * iu) << 24);
        vn[(size_t)row * 192 + lane + 64 * c] = pa;
        un[(size_t)row * 192 + lane + 64 * c] = pb;
    }
    if (lane == 0) diag[row] = sd * iv * iu * TAU_INV / (FP8_SCALE * FP8_SCALE);
}

// ------- Kernel 2: 128x128 fp8 MX MFMA tile (BK=64), XOR-swizzled LDS, 1-barrier dbuf -------
__global__ __launch_bounds__(256, 3) void simexp_kernel(const u8* __restrict__ vn,
                                                        const u8* __restrict__ un,
                                                        float* __restrict__ rowP,
                                                        float* __restrict__ colP) {
    // double-buffered staging: [buf][row][chunk], 64B rows, chunk c holds global chunk c^((r>>1)&3)
    __shared__ __align__(64) u8 As[2 * 128 * 64];
    __shared__ __align__(64) u8 Bs[2 * 128 * 64];
    __shared__ float rowLds[2][128];
    __shared__ float colLds[2][128];

    const int tid  = threadIdx.x;
    const int wid  = tid >> 6;
    const int lane = tid & 63;
    const int l32  = lane & 31;
    const int h    = lane >> 5;
    const int wr = wid >> 1, wc = wid & 1;

    // 8x8 chunked grid for L2 locality
    const int id = blockIdx.x;
    const int chunk = id >> 6;
    const int li = id & 63;
    const int rb = ((chunk >> 3) << 3) + (li >> 3);
    const int cb = ((chunk & 7) << 3) + (li & 7);

    // staging lane map: row sr = lane>>2, LDS chunk c = lane&3, global chunk = c ^ ((sr>>1)&3)
    const int sr = lane >> 2;
    const int sc = (((lane & 3) ^ ((lane >> 3) & 3)) << 4);
    const u8* Ag0 = vn + (size_t)(rb * 128 + wid * 32 + sr) * D_SZ + sc;
    const u8* Bg0 = un + (size_t)(cb * 128 + wid * 32 + sr) * D_SZ + sc;
    const size_t rstep = (size_t)16 * D_SZ;
    u8* AsW = As + (wid * 32) * 64;   // wave-uniform LDS base (buf 0)
    u8* BsW = Bs + (wid * 32) * 64;

    f32x16 acc[2][2];
#pragma unroll
    for (int i = 0; i < 2; ++i)
#pragma unroll
        for (int j = 0; j < 2; ++j)
#pragma unroll
            for (int r = 0; r < 16; ++r) acc[i][j][r] = 0.f;

    // prologue: stage tile 0 into buffer 0
    gld_lds16(Ag0, AsW);
    gld_lds16(Ag0 + rstep, AsW + 16 * 64);
    gld_lds16(Bg0, BsW);
    gld_lds16(Bg0 + rstep, BsW + 16 * 64);

    const int s4 = (l32 >> 1) & 3;
    const int loA = ((2 * h) ^ s4) << 4;       // lo-chunk byte offset within row
    const int hiA = ((2 * h + 1) ^ s4) << 4;

    for (int it = 0; it < 12; ++it) {
        __syncthreads();   // staging of buf[it&1] complete; prior reads of buf[(it+1)&1] done
        const int cur = (it & 1) * 8192;
        if (it + 1 < 12) {
            const int nxt = ((it + 1) & 1) * 8192;
            const int k0 = (it + 1) * 64;
            gld_lds16(Ag0 + k0, AsW + nxt);
            gld_lds16(Ag0 + rstep + k0, AsW + nxt + 16 * 64);
            gld_lds16(Bg0 + k0, BsW + nxt);
            gld_lds16(Bg0 + rstep + k0, BsW + nxt + 16 * 64);
        }
        i32x8 af[2], bf[2];
#pragma unroll
        for (int i = 0; i < 2; ++i) {
            const u8* arow = As + cur + (wr * 64 + i * 32 + l32) * 64;
            i32x4 lo = *(const i32x4*)(arow + loA);
            i32x4 hi = *(const i32x4*)(arow + hiA);
            af[i][0] = lo[0]; af[i][1] = lo[1]; af[i][2] = lo[2]; af[i][3] = lo[3];
            af[i][4] = hi[0]; af[i][5] = hi[1]; af[i][6] = hi[2]; af[i][7] = hi[3];
        }
#pragma unroll
        for (int j = 0; j < 2; ++j) {
            const u8* brow = Bs + cur + (wc * 64 + j * 32 + l32) * 64;
            i32x4 lo = *(const i32x4*)(brow + loA);
            i32x4 hi = *(const i32x4*)(brow + hiA);
            bf[j][0] = lo[0]; bf[j][1] = lo[1]; bf[j][2] = lo[2]; bf[j][3] = lo[3];
            bf[j][4] = hi[0]; bf[j][5] = hi[1]; bf[j][6] = hi[2]; bf[j][7] = hi[3];
        }
#pragma unroll
        for (int i = 0; i < 2; ++i)
#pragma unroll
            for (int j = 0; j < 2; ++j)
                acc[i][j] = __builtin_amdgcn_mfma_scale_f32_32x32x64_f8f6f4(
                    af[i], bf[j], acc[i][j], 0, 0, 0, 0x7F7F7F7F, 0, 0x7F7F7F7F);
    }

    // Epilogue. 32x32 C/D layout: col = lane&31, row = (reg&3) + 8*(reg>>2) + 4*h
    float rowAcc[32];   // [i*16 + reg]
    float colAcc[2];    // [j]
#pragma unroll
    for (int t = 0; t < 32; ++t) rowAcc[t] = 0.f;
    colAcc[0] = 0.f; colAcc[1] = 0.f;
#pragma unroll
    for (int i = 0; i < 2; ++i)
#pragma unroll
        for (int j = 0; j < 2; ++j)
#pragma unroll
            for (int r = 0; r < 16; ++r) {
                float e = exp2f(acc[i][j][r] * ESCALE);
                rowAcc[i * 16 + r] += e;
                colAcc[j] += e;
            }
    // row sums: reduce across the 32 cols (lanes with same h)
#pragma unroll
    for (int m = 1; m < 32; m <<= 1)
#pragma unroll
        for (int t = 0; t < 32; ++t) rowAcc[t] += __shfl_xor(rowAcc[t], m);
    // col sums: add the other h half (rows)
    colAcc[0] += __shfl_xor(colAcc[0], 32);
    colAcc[1] += __shfl_xor(colAcc[1], 32);

    __syncthreads();  // re-use LDS region barriers: all K-loop LDS traffic done
    // writers: row (i,reg) written by lanes with l32==reg (one per h)
#pragma unroll
    for (int i = 0; i < 2; ++i)
#pragma unroll
        for (int t = 0; t < 16; ++t)
            if (l32 == t) {
                int row = wr * 64 + i * 32 + (t & 3) + 8 * (t >> 2) + 4 * h;
                rowLds[wc][row] = rowAcc[i * 16 + t];
            }
    if (h == 0) {
#pragma unroll
        for (int j = 0; j < 2; ++j)
            colLds[wr][wc * 64 + j * 32 + l32] = colAcc[j];
    }
    __syncthreads();
    if (tid < 128) {
        rowP[(size_t)cb * B_SZ + rb * 128 + tid] = rowLds[0][tid] + rowLds[1][tid];
    } else {
        const int t = tid - 128;
        colP[(size_t)rb * B_SZ + cb * 128 + t] = colLds[0][t] + colLds[1][t];
    }
}

// ---------------- Kernel 3: reduce partials, log, subtract diag, mean ----------------
__global__ __launch_bounds__(256) void finalize_kernel(const float* __restrict__ rowP,
                                                       const float* __restrict__ colP,
                                                       const float* __restrict__ diag,
                                                       float* __restrict__ out) {
    const int i = blockIdx.x * 256 + threadIdx.x;
    float rs = 0.f, cs = 0.f;
#pragma unroll 8
    for (int p = 0; p < 64; ++p) {
        rs += rowP[(size_t)p * B_SZ + i];
        cs += colP[(size_t)p * B_SZ + i];
    }
    float contrib = (0.75f * logf(rs) + 0.25f * logf(cs) - diag[i]) * (1.0f / (float)B_SZ);
#pragma unroll
    for (int m = 1; m < 64; m <<= 1) contrib += __shfl_xor(contrib, m);
    __shared__ float red[4];
    const int wid = threadIdx.x >> 6, lane = threadIdx.x & 63;
    if (lane == 0) red[wid] = contrib;
    __syncthreads();
    if (threadIdx.x == 0) atomicAdd(out, red[0] + red[1] + red[2] + red[3]);
}

extern "C" void kernel_launch(void* const* d_in, const int* in_sizes, int n_in,
                              void* d_out, int out_size, void* d_ws, size_t ws_size,
                              hipStream_t stream) {
    const float* v = (const float*)d_in[0];
    const float* u = (const float*)d_in[1];
    char* ws = (char*)d_ws;
    // workspace layout (~16.7 MB)
    u8* vn8    = (u8*)(ws);                     // 8192*768    = 6,291,456
    u8* un8    = (u8*)(ws + 6291456);           // 6,291,456
    float* dg  = (float*)(ws + 12582912);       // 8192*4      = 32,768
    float* rwp = (float*)(ws + 12615680);       // 64*8192*4   = 2,097,152
    float* clp = (float*)(ws + 14712832);       // 2,097,152
    float* out = (float*)d_out;

    hipMemsetAsync(out, 0, sizeof(float), stream);
    hipLaunchKernelGGL(norm_kernel, dim3(2048), dim3(256), 0, stream,
                       (const float4*)v, (const float4*)u, (u32*)vn8, (u32*)un8, dg);
    hipLaunchKernelGGL(simexp_kernel, dim3(4096), dim3(256), 0, stream, vn8, un8, rwp, clp);
    hipLaunchKernelGGL(finalize_kernel, dim3(B_SZ / 256), dim3(256), 0, stream, rwp, clp, dg, out);
}